// Round 13
// baseline (495.209 us; speedup 1.0000x reference)
//
#include <hip/hip_runtime.h>

typedef _Float16 v8h __attribute__((ext_vector_type(8)));
typedef float f32x4 __attribute__((ext_vector_type(4)));

#define BB 128
#define TT 512
#define NN 200
#define START_IDX 1
#define END_IDX 2

#define NT 512   // 8 waves
#define NCOL 16  // batch columns per block
#define SP 232   // p stride in halves (464B, 16B-aligned)
#define NBLK (BB / NCOL) // 8

__device__ __forceinline__ void sync_lds() {
  asm volatile("s_waitcnt lgkmcnt(0)" ::: "memory");
  __builtin_amdgcn_s_barrier();
}

__device__ __forceinline__ v8h zero8() {
  v8h r;
#pragma unroll
  for (int e = 0; e < 8; ++e) r[e] = (_Float16)0.f;
  return r;
}

__global__ __attribute__((amdgpu_flat_work_group_size(NT, NT),
                          amdgpu_waves_per_eu(2, 2)))
void crf_fwd_kernel(const float* __restrict__ unary, const int* __restrict__ tags,
                    const int* __restrict__ lengths, const float* __restrict__ trans,
                    float* __restrict__ ws) {
  const int blk = blockIdx.x; // 0..7
  const int b0 = blk * NCOL;
  const int tid = threadIdx.x;
  const int lane = tid & 63;
  const int wave = tid >> 6; // 0..7
  const int m15 = lane & 15; // A row-in-tile / B,D column (batch)
  const int g = lane >> 4;   // 0..3: k-group (A,B) / row-group (D)

  // Tile assignment (16-row tiles, 13 tiles = rows 0..207; tile 12 rows>=200 zero):
  const bool two = (wave < 5);
  const int ta = two ? 2 * wave : wave + 5; // w5,6,7 -> 10,11,12
  const int tb = 2 * wave + 1;              // valid iff two
  const int ra = 16 * ta, rbT = 16 * tb;

  // p: fp16 col-major [2 bufs][16 cols][SP rows]; rows 200..231 stay 0.
  __shared__ __align__(16) _Float16 pL[2][NCOL * SP];
  __shared__ __align__(16) float padsL[2][NCOL * 8]; // per-(col,wave) partial max
  __shared__ __align__(16) float gred[NCOL * 8];
  __shared__ float goldL[NCOL];
  __shared__ float a2L[NCOL];

  // ---- init p(buf0) = e_START per col; buf1 = 0; pads0: wave0 owns row START
  for (int i = tid; i < NCOL * SP; i += NT) {
    const int r = i - (i / SP) * SP;
    pL[0][i] = (r == START_IDX) ? (_Float16)1.0f : (_Float16)0.0f;
    pL[1][i] = (_Float16)0.0f;
  }
  for (int i = tid; i < NCOL * 8; i += NT)
    padsL[0][i] = ((i & 7) == 0) ? 1.0f : 0.0f;

  const int lenc = lengths[b0 + m15];
  int maxlen = lenc;
#pragma unroll
  for (int k = 1; k < 16; k <<= 1) maxlen = max(maxlen, __shfl_xor(maxlen, k, 64));

  // ---- A fragments: E = exp(trans); row = tilebase+m15, k = 32kc+8g+e
  v8h Afa[7], Afb[7];
  auto mkfrag = [&](int row, int kc) -> v8h {
    const int k8 = 32 * kc + 8 * g;
    if (row < NN && k8 < NN) {
      const float4 a = *reinterpret_cast<const float4*>(trans + row * NN + k8);
      const float4 b = *reinterpret_cast<const float4*>(trans + row * NN + k8 + 4);
      v8h r;
      r[0] = (_Float16)__expf(a.x); r[1] = (_Float16)__expf(a.y);
      r[2] = (_Float16)__expf(a.z); r[3] = (_Float16)__expf(a.w);
      r[4] = (_Float16)__expf(b.x); r[5] = (_Float16)__expf(b.y);
      r[6] = (_Float16)__expf(b.z); r[7] = (_Float16)__expf(b.w);
      return r;
    }
    return zero8();
  };
#pragma unroll
  for (int kc = 0; kc < 7; ++kc) {
    Afa[kc] = mkfrag(ra + m15, kc);
    Afb[kc] = two ? mkfrag(rbT + m15, kc) : zero8();
  }

  // ---- gold path scores: col = m15, 32 t-slices (g,wave)
  {
    const int bG = b0 + m15;
    const int sG = tid >> 4; // 0..31
    float gacc = 0.f;
    for (int t = sG; t < lenc; t += 32) {
      const int cur = tags[bG * TT + t];
      const int prev = (t == 0) ? START_IDX : tags[bG * TT + t - 1];
      gacc += trans[cur * NN + prev] + unary[(size_t)bG * (TT * NN) + t * NN + cur];
    }
    gacc += __shfl_xor(gacc, 16, 64);
    gacc += __shfl_xor(gacc, 32, 64);
    if (g == 0) gred[m15 * 8 + wave] = gacc;
    __syncthreads();
    if (tid < 16) {
      const float4 g0 = *reinterpret_cast<const float4*>(&gred[tid * 8]);
      const float4 g1 = *reinterpret_cast<const float4*>(&gred[tid * 8 + 4]);
      const int lt = tags[(b0 + tid) * TT + lengths[b0 + tid] - 1];
      goldL[tid] = g0.x + g0.y + g0.z + g0.w + g1.x + g1.y + g1.z + g1.w +
                   trans[END_IDX * NN + lt];
    }
  }

  // ---- u prefetch (2-step rename): col m15, rows tilebase + 4g..+3
  const float* uCol = unary + (size_t)(b0 + m15) * (TT * NN);
  const bool ldA_ok = (ra + 4 * g + 3) < NN; // tile12 g>=2 would touch rows>=200
  auto uload = [&](int t, int rb, bool ok) -> float4 {
    if (ok) return *reinterpret_cast<const float4*>(uCol + t * NN + rb + 4 * g);
    return float4{0.f, 0.f, 0.f, 0.f};
  };
  float4 eaA = uload(0, ra, ldA_ok), ebA = uload(0, rbT, two);
  float4 eaB = uload(1, ra, ldA_ok), ebB = uload(1, rbT, two);

  float sc2 = 0.f; // per-col running scale (log2): alpha = sc2*ln2 + log p
  __syncthreads();

  auto STEP = [&](int t, float4& ea, float4& eb) {
    const int rb = t & 1, wb = rb ^ 1;

    // reads from buf rb (written last step, barrier'd)
    const float4 pv0 = *reinterpret_cast<const float4*>(&padsL[rb][m15 * 8]);
    const float4 pv1 = *reinterpret_cast<const float4*>(&padsL[rb][m15 * 8 + 4]);
    uint4 Bq[7];
#pragma unroll
    for (int kc = 0; kc < 7; ++kc)
      Bq[kc] = *reinterpret_cast<const uint4*>(
          reinterpret_cast<const char*>(&pL[rb][0]) + 2 * (m15 * SP + 32 * kc + 8 * g));

    // overlap ds_read latency with exp(u) of the consumed set
    float exa[4], exb[4];
    exa[0] = __expf(ea.x); exa[1] = __expf(ea.y);
    exa[2] = __expf(ea.z); exa[3] = __expf(ea.w);
    exb[0] = __expf(eb.x); exb[1] = __expf(eb.y);
    exb[2] = __expf(eb.z); exb[3] = __expf(eb.w);

    const float M = fmaxf(fmaxf(fmaxf(pv0.x, pv0.y), fmaxf(pv0.z, pv0.w)),
                          fmaxf(fmaxf(pv1.x, pv1.y), fmaxf(pv1.z, pv1.w)));
    const float rcpM = __builtin_amdgcn_rcpf(M);
    const bool pr = (t < lenc);
    sc2 += pr ? __log2f(M) : 0.f;

    f32x4 aca = {0.f, 0.f, 0.f, 0.f};
    f32x4 acb = {0.f, 0.f, 0.f, 0.f};
#pragma unroll
    for (int kc = 0; kc < 7; ++kc) {
      const v8h Bk = __builtin_bit_cast(v8h, Bq[kc]);
      aca = __builtin_amdgcn_mfma_f32_16x16x32_f16(Afa[kc], Bk, aca, 0, 0, 0);
      if (two)
        acb = __builtin_amdgcn_mfma_f32_16x16x32_f16(Afb[kc], Bk, acb, 0, 0, 0);
    }

    // issue u prefetch for t+2 into the consumed set (2-step slack)
    const int t2 = (t + 2 < TT) ? t + 2 : TT - 1;
    ea = uload(t2, ra, ldA_ok);
    if (two) eb = uload(t2, rbT, two);

    // epilogue: p_new = ac * exp(u) / M; write buf wb; D row = tilebase+4g+reg
    float mx = 0.f;
    auto epi = [&](const f32x4& ac, const float* ex, int rbase) {
      const float p0 = ac[0] * ex[0] * rcpM, p1 = ac[1] * ex[1] * rcpM;
      const float p2 = ac[2] * ex[2] * rcpM, p3 = ac[3] * ex[3] * rcpM;
      mx = fmaxf(mx, fmaxf(fmaxf(p0, p1), fmaxf(p2, p3)));
      uint2 wv;
      wv.x = __builtin_bit_cast(unsigned, __builtin_amdgcn_cvt_pkrtz(p0, p1));
      wv.y = __builtin_bit_cast(unsigned, __builtin_amdgcn_cvt_pkrtz(p2, p3));
      if (pr)
        *reinterpret_cast<uint2*>(reinterpret_cast<char*>(&pL[wb][0]) +
                                  2 * (m15 * SP + rbase + 4 * g)) = wv;
    };
    epi(aca, exa, ra);
    if (two) epi(acb, exb, rbT);

    // per-col partial max for this wave's tiles
    mx = fmaxf(mx, __shfl_xor(mx, 16, 64));
    mx = fmaxf(mx, __shfl_xor(mx, 32, 64));
    if (g == 0 && pr) padsL[wb][m15 * 8 + wave] = mx;

    sync_lds(); // single barrier (vmcnt NOT drained; u loads stay in flight)
  };

  int t = 0;
  for (; t + 1 < maxlen; t += 2) {
    STEP(t, eaA, ebA);
    STEP(t + 1, eaB, ebB);
  }
  if (t < maxlen) STEP(t, eaA, ebA);

  // ---- terminal (waves 0..3): fwd[col] = sc2*ln2 + log(sum_j p[j] e^{trans[END,j]})
  if (wave == 0 && g == 0) a2L[m15] = sc2;
  __syncthreads();
  if (wave < 4) {
    const int colT = wave * 4 + g;
    const int fb = lengths[b0 + colT] & 1; // buffer written at step len-1
    float sum = 0.f;
#pragma unroll
    for (int k = 0; k < 13; ++k) {
      const int j = m15 + 16 * k;
      if (j < NN) {
        const float pj = (float)pL[fb][colT * SP + j];
        sum += pj * __expf(trans[END_IDX * NN + j]);
      }
    }
#pragma unroll
    for (int k = 1; k < 16; k <<= 1) sum += __shfl_xor(sum, k, 64);
    if (m15 == 0) {
      const float fwd = a2L[colT] * 0.6931471805599453f + __logf(sum);
      ws[b0 + colT] = fwd - goldL[colT];
    }
  }
}

__global__ void crf_reduce_kernel(const float* __restrict__ wsIn,
                                  float* __restrict__ out) {
  const int tid = threadIdx.x; // 128 threads
  float v = wsIn[tid];
#pragma unroll
  for (int k = 32; k >= 1; k >>= 1) v += __shfl_xor(v, k, 64);
  __shared__ float s2[2];
  if ((tid & 63) == 0) s2[tid >> 6] = v;
  __syncthreads();
  if (tid == 0) out[0] = (s2[0] + s2[1]) * (1.0f / 128.0f);
}

extern "C" void kernel_launch(void* const* d_in, const int* in_sizes, int n_in,
                              void* d_out, int out_size, void* d_ws, size_t ws_size,
                              hipStream_t stream) {
  const float* unary = (const float*)d_in[0];
  const int* tags = (const int*)d_in[1];
  const int* lengths = (const int*)d_in[2];
  const float* trans = (const float*)d_in[3];
  float* ws = (float*)d_ws;
  float* out = (float*)d_out;

  crf_fwd_kernel<<<NBLK, NT, 0, stream>>>(unary, tags, lengths, trans, ws);
  crf_reduce_kernel<<<1, 128, 0, stream>>>(ws, out);
}

// Round 14
// 444.880 us; speedup vs baseline: 1.1131x; 1.1131x over previous
//
#include <hip/hip_runtime.h>

typedef _Float16 v2h __attribute__((ext_vector_type(2)));

#define BB 128
#define TT 512
#define NN 200
#define START_IDX 1
#define END_IDX 2

#define NT 256        // 4 waves
#define QI 28         // valid halves per chunk (chunk owner c = lane&7)
#define CH 40         // padded halves per chunk: 80B stride, conflict-free banks
#define PSLOTS (8*CH) // 320
#define NBLK 64       // 2 chains per block

__device__ __forceinline__ float fdot2(v2h a, v2h b, float c) {
  return __builtin_amdgcn_fdot2(a, b, c, false);
}

// LDS-only barrier: does NOT drain vmcnt (global u-prefetch stays in flight).
__device__ __forceinline__ void sync_lds() {
  asm volatile("s_waitcnt lgkmcnt(0)" ::: "memory");
  __builtin_amdgcn_s_barrier();
}

// sum over 8 consecutive lanes; all 8 lanes get the sum
__device__ __forceinline__ float dpp_add8(float x) {
  int v;
  v = __builtin_amdgcn_mov_dpp(__float_as_int(x), 0xB1, 0xF, 0xF, true);
  x += __int_as_float(v);
  v = __builtin_amdgcn_mov_dpp(__float_as_int(x), 0x4E, 0xF, 0xF, true);
  x += __int_as_float(v);
  v = __builtin_amdgcn_mov_dpp(__float_as_int(x), 0x141, 0xF, 0xF, true);
  x += __int_as_float(v);
  return x;
}

// max over 8 consecutive lanes; all 8 lanes get the max
__device__ __forceinline__ float dpp_max8(float x) {
  int v;
  v = __builtin_amdgcn_mov_dpp(__float_as_int(x), 0xB1, 0xF, 0xF, true);
  x = fmaxf(x, __int_as_float(v));
  v = __builtin_amdgcn_mov_dpp(__float_as_int(x), 0x4E, 0xF, 0xF, true);
  x = fmaxf(x, __int_as_float(v));
  v = __builtin_amdgcn_mov_dpp(__float_as_int(x), 0x141, 0xF, 0xF, true);
  x = fmaxf(x, __int_as_float(v));
  return x;
}

// full-wave max (nonneg inputs), pure DPP; result valid in lane 63
__device__ __forceinline__ float wave_max_dpp(float x) {
  int v;
  v = __builtin_amdgcn_mov_dpp(__float_as_int(x), 0xB1, 0xF, 0xF, true);
  x = fmaxf(x, __int_as_float(v));
  v = __builtin_amdgcn_mov_dpp(__float_as_int(x), 0x4E, 0xF, 0xF, true);
  x = fmaxf(x, __int_as_float(v));
  v = __builtin_amdgcn_mov_dpp(__float_as_int(x), 0x141, 0xF, 0xF, true);
  x = fmaxf(x, __int_as_float(v));
  v = __builtin_amdgcn_mov_dpp(__float_as_int(x), 0x140, 0xF, 0xF, true);
  x = fmaxf(x, __int_as_float(v));
  v = __builtin_amdgcn_mov_dpp(__float_as_int(x), 0x142, 0xF, 0xF, true);
  x = fmaxf(x, __int_as_float(v));
  v = __builtin_amdgcn_mov_dpp(__float_as_int(x), 0x143, 0xF, 0xF, true);
  x = fmaxf(x, __int_as_float(v));
  return x;
}

__global__ __attribute__((amdgpu_flat_work_group_size(NT, NT),
                          amdgpu_waves_per_eu(1, 1)))
void crf_fwd_kernel(
    const float* __restrict__ unary, const int* __restrict__ tags,
    const int* __restrict__ lengths, const float* __restrict__ trans,
    float* __restrict__ ws) {
  const int blk = blockIdx.x;
  const int bA = 2 * blk, bB = 2 * blk + 1;
  const int tid = threadIdx.x;
  const int lane = tid & 63;
  const int wave = tid >> 6;       // 0..3
  const int c = lane & 7;          // i-chunk: i in [28c, 28c+28)
  const int g = (lane >> 3) & 7;   // group within wave
  const int gg = (wave << 3) + g;  // global group id, 0..31
  const int lenA = lengths[bA], lenB = lengths[bB];
  const int maxlen = max(lenA, lenB);

  // Two chains share the block; each has its own double-buffered p (fp16,
  // 80B chunk stride). Pad halves 28..29 of chunk w carry (as f32 bits) wave
  // w's partial row-max; rides the q3 read (never read as fp16).
  __shared__ __align__(16) _Float16 pH[2][2][PSLOTS]; // [chain][buf]
  // Occupancy pin: 92KB -> 1 block/CU -> (1,1) unlocks the VGPR budget.
  // big[0..7]=red, big[8..15]=redE, big[16]=goldA, big[17]=goldB.
  __shared__ __align__(16) float big[23040];

  const float* upA = unary + (size_t)bA * (TT * NN);
  const float* upB = unary + (size_t)bB * (TT * NN);

  // ---- init both chains: p0 = e_START in buf0, buf1 = 0, pads zeroed
  for (int i = tid; i < PSLOTS; i += NT) {
    const _Float16 v = (i == START_IDX) ? (_Float16)1.0f : (_Float16)0.0f;
    pH[0][0][i] = v; pH[0][1][i] = (_Float16)0.0f;
    pH[1][0][i] = v; pH[1][1][i] = (_Float16)0.0f;
  }
  __syncthreads(); // order the aliasing f32 pad stores after the fp16 init
  if (tid == 0) {
    *reinterpret_cast<float*>(&pH[0][0][28]) = 1.0f; // max(p0) = 1
    *reinterpret_cast<float*>(&pH[1][0][28]) = 1.0f;
  }
  if (maxlen < 0) big[23039] = 0.f; // keeps the pin alive

  // ---- E = exp(trans) fp16, SHARED by both chains:
  // group gg owns rows 6*gg+r (r<6) -> 0..191; c==6,g<2 extra row 192+2w+g.
  v2h Er[7][QI / 2];
#pragma unroll
  for (int r = 0; r < 7; ++r) {
    int j; bool valid;
    if (r < 6) { j = 6 * gg + r; valid = true; }
    else       { j = 192 + 2 * wave + g; valid = (g < 2); }
    if (valid) {
      if (c < 7) {
        const float4* t4 = reinterpret_cast<const float4*>(trans + j * NN + c * QI);
#pragma unroll
        for (int k = 0; k < 7; ++k) {
          const float4 tv = t4[k];
          Er[r][2 * k + 0] = v2h{(_Float16)__expf(tv.x), (_Float16)__expf(tv.y)};
          Er[r][2 * k + 1] = v2h{(_Float16)__expf(tv.z), (_Float16)__expf(tv.w)};
        }
      } else {
        const float4 tv = *reinterpret_cast<const float4*>(trans + j * NN + 196);
        Er[r][0] = v2h{(_Float16)__expf(tv.x), (_Float16)__expf(tv.y)};
        Er[r][1] = v2h{(_Float16)__expf(tv.z), (_Float16)__expf(tv.w)};
#pragma unroll
        for (int k = 2; k < QI / 2; ++k) Er[r][k] = v2h{(_Float16)0, (_Float16)0};
      }
    } else {
#pragma unroll
      for (int k = 0; k < QI / 2; ++k) Er[r][k] = v2h{(_Float16)0, (_Float16)0};
    }
  }

  // ---- gold path scores (grid-stride per chain)
  {
    float ga = 0.f, gb = 0.f;
    for (int t = tid; t < lenA; t += NT) {
      const int cur = tags[bA * TT + t];
      const int prev = (t == 0) ? START_IDX : tags[bA * TT + t - 1];
      ga += trans[cur * NN + prev] + upA[(size_t)t * NN + cur];
    }
    for (int t = tid; t < lenB; t += NT) {
      const int cur = tags[bB * TT + t];
      const int prev = (t == 0) ? START_IDX : tags[bB * TT + t - 1];
      gb += trans[cur * NN + prev] + upB[(size_t)t * NN + cur];
    }
#pragma unroll
    for (int k = 32; k >= 1; k >>= 1) {
      ga += __shfl_xor(ga, k, 64);
      gb += __shfl_xor(gb, k, 64);
    }
    if (lane == 0) { big[wave] = ga; big[4 + wave] = gb; }
    __syncthreads();
    if (tid == 0) {
      const int ltA = tags[bA * TT + lenA - 1];
      const int ltB = tags[bB * TT + lenB - 1];
      big[16] = big[0] + big[1] + big[2] + big[3] + trans[END_IDX * NN + ltA];
      big[17] = big[4] + big[5] + big[6] + big[7] + trans[END_IDX * NN + ltB];
    }
  }

  // ---- row ownership (same for both chains)
  const bool erow = (c < 6) || (c == 6 && g < 2);
  const int jrow = (c < 6) ? (6 * gg + c) : (192 + 2 * wave + g);
  const int wh = (jrow / QI) * CH + (jrow % QI);
  const float* upjA = upA + jrow;
  const float* upjB = upB + jrow;

  // u pipelines (unroll-2 renamed, per chain)
  float uexpCA = 0.f, a0r = 0.f, a1r = 0.f; // a0r/a1r: chain A rename regs
  float uexpCB = 0.f, b0r = 0.f, b1r = 0.f;
  if (erow) {
    uexpCA = __expf(upjA[0]); a1r = upjA[(size_t)NN];
    uexpCB = __expf(upjB[0]); b1r = upjB[(size_t)NN];
  }
  float scA = 0.f, scB = 0.f; // per-chain scale (log2): alpha = sc*ln2 + log p
  __syncthreads();

  auto STEP = [&](int t, float& conA, float& issA, float& conB, float& issB) {
    const int rb = t & 1, wb = rb ^ 1;

    // issue all LDS reads up front (both chains -> deep lgkm pipeline)
    const _Float16* pcA = &pH[0][rb][c * CH];
    const _Float16* pcB = &pH[1][rb][c * CH];
    const uint4 qA0 = reinterpret_cast<const uint4*>(pcA)[0];
    const uint4 qA1 = reinterpret_cast<const uint4*>(pcA)[1];
    const uint4 qA2 = reinterpret_cast<const uint4*>(pcA)[2];
    const uint4 qA3 = *reinterpret_cast<const uint4*>(pcA + 24);
    const uint4 qB0 = reinterpret_cast<const uint4*>(pcB)[0];
    const uint4 qB1 = reinterpret_cast<const uint4*>(pcB)[1];
    const uint4 qB2 = reinterpret_cast<const uint4*>(pcB)[2];
    const uint4 qB3 = *reinterpret_cast<const uint4*>(pcB + 24);

    // issue u prefetch for t+2 early (consumed late next step)
    if (erow) {
      const int tiA = (t + 2 < lenA) ? (t + 2) : (lenA - 1);
      const int tiB = (t + 2 < lenB) ? (t + 2) : (lenB - 1);
      issA = upjA[(size_t)(tiA * NN)];
      issB = upjB[(size_t)(tiB * NN)];
    }

    // scales (per chain)
    const float MA = dpp_max8(__int_as_float(qA3.z));
    const float MB = dpp_max8(__int_as_float(qB3.z));
    const float rMA = __builtin_amdgcn_rcpf(MA);
    const float rMB = __builtin_amdgcn_rcpf(MB);
    const bool prA = (t < lenA), prB = (t < lenB);
    scA += prA ? __log2f(MA) : 0.f;
    scB += prB ? __log2f(MB) : 0.f;
    const float fA = uexpCA * rMA;
    const float fB = uexpCB * rMB;

    // dots: two independent chains interleave -> fills latency gaps
    const unsigned pwA[14] = {qA0.x, qA0.y, qA0.z, qA0.w, qA1.x, qA1.y, qA1.z,
                              qA1.w, qA2.x, qA2.y, qA2.z, qA2.w, qA3.x, qA3.y};
    const unsigned pwB[14] = {qB0.x, qB0.y, qB0.z, qB0.w, qB1.x, qB1.y, qB1.z,
                              qB1.w, qB2.x, qB2.y, qB2.z, qB2.w, qB3.x, qB3.y};
    float aA0 = 0.f, aA1 = 0.f, aA2 = 0.f, aA3 = 0.f, aA4 = 0.f, aA5 = 0.f, aA6 = 0.f;
    float aB0 = 0.f, aB1 = 0.f, aB2 = 0.f, aB3 = 0.f, aB4 = 0.f, aB5 = 0.f, aB6 = 0.f;
#pragma unroll
    for (int k = 0; k < QI / 2; ++k) {
      const v2h pkA = __builtin_bit_cast(v2h, pwA[k]);
      const v2h pkB = __builtin_bit_cast(v2h, pwB[k]);
      aA0 = fdot2(Er[0][k], pkA, aA0); aB0 = fdot2(Er[0][k], pkB, aB0);
      aA1 = fdot2(Er[1][k], pkA, aA1); aB1 = fdot2(Er[1][k], pkB, aB1);
      aA2 = fdot2(Er[2][k], pkA, aA2); aB2 = fdot2(Er[2][k], pkB, aB2);
      aA3 = fdot2(Er[3][k], pkA, aA3); aB3 = fdot2(Er[3][k], pkB, aB3);
      aA4 = fdot2(Er[4][k], pkA, aA4); aB4 = fdot2(Er[4][k], pkB, aB4);
      aA5 = fdot2(Er[5][k], pkA, aA5); aB5 = fdot2(Er[5][k], pkB, aB5);
      aA6 = fdot2(Er[6][k], pkA, aA6); aB6 = fdot2(Er[6][k], pkB, aB6);
    }
    float sA = dpp_add8(aA0), sB = dpp_add8(aB0);
    {
      const float t1 = dpp_add8(aA1); sA = (c == 1) ? t1 : sA;
      const float t2 = dpp_add8(aA2); sA = (c == 2) ? t2 : sA;
      const float t3 = dpp_add8(aA3); sA = (c == 3) ? t3 : sA;
      const float t4 = dpp_add8(aA4); sA = (c == 4) ? t4 : sA;
      const float t5 = dpp_add8(aA5); sA = (c == 5) ? t5 : sA;
      const float t6 = dpp_add8(aA6); sA = (c == 6) ? t6 : sA;
      const float u1 = dpp_add8(aB1); sB = (c == 1) ? u1 : sB;
      const float u2 = dpp_add8(aB2); sB = (c == 2) ? u2 : sB;
      const float u3 = dpp_add8(aB3); sB = (c == 3) ? u3 : sB;
      const float u4 = dpp_add8(aB4); sB = (c == 4) ? u4 : sB;
      const float u5 = dpp_add8(aB5); sB = (c == 5) ? u5 : sB;
      const float u6 = dpp_add8(aB6); sB = (c == 6) ? u6 : sB;
    }

    const float pnA = sA * fA, pnB = sB * fB;
    if (erow && prA) pH[0][wb][wh] = (_Float16)pnA;
    if (erow && prB) pH[1][wb][wh] = (_Float16)pnB;
    const float mxA = wave_max_dpp((c < 6) ? pnA : 0.f); // lane 63 valid
    const float mxB = wave_max_dpp((c < 6) ? pnB : 0.f);
    if (lane == 63) {
      if (prA) *reinterpret_cast<float*>(&pH[0][wb][wave * CH + 28]) = mxA;
      if (prB) *reinterpret_cast<float*>(&pH[1][wb][wave * CH + 28]) = mxB;
    }

    uexpCA = erow ? __expf(conA) : 0.f;
    uexpCB = erow ? __expf(conB) : 0.f;
    sync_lds();
  };

  int t = 0;
  for (; t + 1 < maxlen; t += 2) {
    STEP(t,     a1r, a0r, b1r, b0r);
    STEP(t + 1, a0r, a1r, b0r, b1r);
  }
  if (t < maxlen) STEP(t, a1r, a0r, b1r, b0r);

  const float AA = scA * 0.6931471805599453f;
  const float AB = scB * 0.6931471805599453f;

  // ---- terminals (both chains in one pass)
  const int fbA = lenA & 1, fbB = lenB & 1;
  float vA = -3e38f, vB = -3e38f;
  if (tid < NN) {
    const int slot = (tid / QI) * CH + (tid % QI);
    const float te = trans[END_IDX * NN + tid];
    const float pA = (float)pH[0][fbA][slot];
    const float pB = (float)pH[1][fbB][slot];
    vA = AA + ((pA > 0.f) ? __logf(pA) : -1e30f) + te;
    vB = AB + ((pB > 0.f) ? __logf(pB) : -1e30f) + te;
  }
  float mA = vA, mB = vB;
#pragma unroll
  for (int k = 32; k >= 1; k >>= 1) {
    mA = fmaxf(mA, __shfl_xor(mA, k, 64));
    mB = fmaxf(mB, __shfl_xor(mB, k, 64));
  }
  if (lane == 0) { big[wave] = mA; big[4 + wave] = mB; }
  __syncthreads();
  mA = fmaxf(fmaxf(big[0], big[1]), fmaxf(big[2], big[3]));
  mB = fmaxf(fmaxf(big[4], big[5]), fmaxf(big[6], big[7]));
  float eA = (tid < NN) ? __expf(vA - mA) : 0.f;
  float eB = (tid < NN) ? __expf(vB - mB) : 0.f;
#pragma unroll
  for (int k = 32; k >= 1; k >>= 1) {
    eA += __shfl_xor(eA, k, 64);
    eB += __shfl_xor(eB, k, 64);
  }
  if (lane == 0) { big[8 + wave] = eA; big[12 + wave] = eB; }
  __syncthreads();
  if (tid == 0) {
    const float sEA = big[8] + big[9] + big[10] + big[11];
    const float sEB = big[12] + big[13] + big[14] + big[15];
    ws[bA] = (mA + __logf(sEA)) - big[16];
    ws[bB] = (mB + __logf(sEB)) - big[17];
  }
}

__global__ void crf_reduce_kernel(const float* __restrict__ wsIn,
                                  float* __restrict__ out) {
  const int tid = threadIdx.x; // 128 threads
  float v = wsIn[tid];
#pragma unroll
  for (int k = 32; k >= 1; k >>= 1) v += __shfl_xor(v, k, 64);
  __shared__ float s2[2];
  if ((tid & 63) == 0) s2[tid >> 6] = v;
  __syncthreads();
  if (tid == 0) out[0] = (s2[0] + s2[1]) * (1.0f / 128.0f);
}

extern "C" void kernel_launch(void* const* d_in, const int* in_sizes, int n_in,
                              void* d_out, int out_size, void* d_ws, size_t ws_size,
                              hipStream_t stream) {
  const float* unary = (const float*)d_in[0];
  const int* tags = (const int*)d_in[1];
  const int* lengths = (const int*)d_in[2];
  const float* trans = (const float*)d_in[3];
  float* ws = (float*)d_ws;
  float* out = (float*)d_out;

  crf_fwd_kernel<<<NBLK, NT, 0, stream>>>(unary, tags, lengths, trans, ws);
  crf_reduce_kernel<<<1, 128, 0, stream>>>(ws, out);
}

// Round 15
// 184.994 us; speedup vs baseline: 2.6769x; 2.4048x over previous
//
#include <hip/hip_runtime.h>

typedef _Float16 v2h __attribute__((ext_vector_type(2)));

#define BB 128
#define TT 512
#define NN 200
#define START_IDX 1
#define END_IDX 2

#define NT 256        // 4 waves
#define QI 28         // valid halves per chunk (chunk owner c = lane&7)
#define CH 40         // padded halves per chunk: 80B stride, conflict-free banks
#define PSLOTS (8*CH) // 320

__device__ __forceinline__ float fdot2(v2h a, v2h b, float c) {
  return __builtin_amdgcn_fdot2(a, b, c, false);
}

// LDS-only barrier: does NOT drain vmcnt (global u-prefetch stays in flight).
__device__ __forceinline__ void sync_lds() {
  asm volatile("s_waitcnt lgkmcnt(0)" ::: "memory");
  __builtin_amdgcn_s_barrier();
}

// sum over 8 consecutive lanes; all 8 lanes get the sum
__device__ __forceinline__ float dpp_add8(float x) {
  int v;
  v = __builtin_amdgcn_mov_dpp(__float_as_int(x), 0xB1, 0xF, 0xF, true);
  x += __int_as_float(v);
  v = __builtin_amdgcn_mov_dpp(__float_as_int(x), 0x4E, 0xF, 0xF, true);
  x += __int_as_float(v);
  v = __builtin_amdgcn_mov_dpp(__float_as_int(x), 0x141, 0xF, 0xF, true);
  x += __int_as_float(v);
  return x;
}

// max over 8 consecutive lanes; all 8 lanes get the max
__device__ __forceinline__ float dpp_max8(float x) {
  int v;
  v = __builtin_amdgcn_mov_dpp(__float_as_int(x), 0xB1, 0xF, 0xF, true);
  x = fmaxf(x, __int_as_float(v));
  v = __builtin_amdgcn_mov_dpp(__float_as_int(x), 0x4E, 0xF, 0xF, true);
  x = fmaxf(x, __int_as_float(v));
  v = __builtin_amdgcn_mov_dpp(__float_as_int(x), 0x141, 0xF, 0xF, true);
  x = fmaxf(x, __int_as_float(v));
  return x;
}

// full-wave max (nonneg inputs), pure DPP; result valid in lane 63
__device__ __forceinline__ float wave_max_dpp(float x) {
  int v;
  v = __builtin_amdgcn_mov_dpp(__float_as_int(x), 0xB1, 0xF, 0xF, true);
  x = fmaxf(x, __int_as_float(v));
  v = __builtin_amdgcn_mov_dpp(__float_as_int(x), 0x4E, 0xF, 0xF, true);
  x = fmaxf(x, __int_as_float(v));
  v = __builtin_amdgcn_mov_dpp(__float_as_int(x), 0x141, 0xF, 0xF, true);
  x = fmaxf(x, __int_as_float(v));
  v = __builtin_amdgcn_mov_dpp(__float_as_int(x), 0x140, 0xF, 0xF, true);
  x = fmaxf(x, __int_as_float(v));
  v = __builtin_amdgcn_mov_dpp(__float_as_int(x), 0x142, 0xF, 0xF, true);
  x = fmaxf(x, __int_as_float(v));
  v = __builtin_amdgcn_mov_dpp(__float_as_int(x), 0x143, 0xF, 0xF, true);
  x = fmaxf(x, __int_as_float(v));
  return x;
}

// One block = one half-chain. Block 2b = forward half of chain b (computes
// a_h = M_{h-1}..M_0 a0, h = len/2 steps); block 2b+1 = backward half
// (computes c_h = M_h^T..M_{len-1}^T r, len-h steps, using E^T).
// Z_b = c_h . a_h, merged in crf_merge_kernel.
__global__ __attribute__((amdgpu_flat_work_group_size(NT, NT),
                          amdgpu_waves_per_eu(1, 1)))
void crf_half_kernel(
    const float* __restrict__ unary, const int* __restrict__ tags,
    const int* __restrict__ lengths, const float* __restrict__ trans,
    float* __restrict__ ws) {
  const int bx = blockIdx.x;
  const int b = bx >> 1;
  const bool isF = (bx & 1) == 0;
  const int tid = threadIdx.x;
  const int lane = tid & 63;
  const int wave = tid >> 6;       // 0..3
  const int c = lane & 7;          // i-chunk: i in [28c, 28c+28)
  const int g = (lane >> 3) & 7;   // group within wave
  const int gg = (wave << 3) + g;  // global group id, 0..31
  const int len = lengths[b];
  const int h = len >> 1;
  const int nsteps = isF ? h : (len - h);

  // double-buffered fp16 vector, 80B chunk stride. Pad halves 28..29 of chunk
  // w carry (as f32 bits) wave w's partial row-max (rides the q3 read).
  __shared__ __align__(16) _Float16 pH[2][PSLOTS];
  // Occupancy pin: 92KB -> 1 block/CU -> (1,1) unlocks the VGPR budget.
  __shared__ __align__(16) float big[23040];

  const float* up = unary + (size_t)b * (TT * NN);

  // ---- init: buf0 = (fwd: e_START, bwd: filled below), buf1 = 0
  for (int i = tid; i < PSLOTS; i += NT) {
    pH[0][i] = (isF && i == START_IDX) ? (_Float16)1.0f : (_Float16)0.0f;
    pH[1][i] = (_Float16)0.0f;
  }
  if (len < 0) big[23039] = 0.f; // keeps the pin alive
  __syncthreads();               // order aliasing f32 pad stores after fp16 init

  // ---- fragments: group gg owns OUTPUT rows 6*gg+r (r<6) -> 0..191;
  //      c==6,g<2 extra row 192+2w+g. fwd: F[j,i]=exp(trans[j,i]);
  //      bwd: F[j,i]=exp(trans[i,j]) (E^T, strided one-time load).
  v2h Er[7][QI / 2];
#pragma unroll
  for (int r = 0; r < 7; ++r) {
    int j; bool valid;
    if (r < 6) { j = 6 * gg + r; valid = true; }
    else       { j = 192 + 2 * wave + g; valid = (g < 2); }
    if (valid) {
      if (isF) {
        if (c < 7) {
          const float4* t4 = reinterpret_cast<const float4*>(trans + j * NN + c * QI);
#pragma unroll
          for (int k = 0; k < 7; ++k) {
            const float4 tv = t4[k];
            Er[r][2 * k + 0] = v2h{(_Float16)__expf(tv.x), (_Float16)__expf(tv.y)};
            Er[r][2 * k + 1] = v2h{(_Float16)__expf(tv.z), (_Float16)__expf(tv.w)};
          }
        } else {
          const float4 tv = *reinterpret_cast<const float4*>(trans + j * NN + 196);
          Er[r][0] = v2h{(_Float16)__expf(tv.x), (_Float16)__expf(tv.y)};
          Er[r][1] = v2h{(_Float16)__expf(tv.z), (_Float16)__expf(tv.w)};
#pragma unroll
          for (int k = 2; k < QI / 2; ++k) Er[r][k] = v2h{(_Float16)0, (_Float16)0};
        }
      } else {
        const int nm = (c < 7) ? 14 : 2; // c==7: only inputs 196..199 valid
#pragma unroll
        for (int m = 0; m < QI / 2; ++m) {
          if (m < nm) {
            const int i0 = c * QI + 2 * m;
            Er[r][m] = v2h{(_Float16)__expf(trans[(size_t)i0 * NN + j]),
                           (_Float16)__expf(trans[(size_t)(i0 + 1) * NN + j])};
          } else {
            Er[r][m] = v2h{(_Float16)0, (_Float16)0};
          }
        }
      }
    } else {
#pragma unroll
      for (int k = 0; k < QI / 2; ++k) Er[r][k] = v2h{(_Float16)0, (_Float16)0};
    }
  }

  // ---- row ownership
  const bool erow = (c < 6) || (c == 6 && g < 2);
  const int jrow = (c < 6) ? (6 * gg + c) : (192 + 2 * wave + g);
  const int wh = (jrow / QI) * CH + (jrow % QI);
  const float* upj = up + jrow;

  // ---- path-specific init
  if (isF) {
    if (tid == 0) *reinterpret_cast<float*>(&pH[0][28]) = 1.0f; // max(p0)=1
    // gold path score
    float gacc = 0.0f;
    for (int t = tid; t < len; t += NT) {
      const int cur = tags[b * TT + t];
      const int prev = (t == 0) ? START_IDX : tags[b * TT + t - 1];
      gacc += trans[cur * NN + prev] + up[(size_t)t * NN + cur];
    }
#pragma unroll
    for (int k = 32; k >= 1; k >>= 1) gacc += __shfl_xor(gacc, k, 64);
    if (lane == 0) big[wave] = gacc;
    __syncthreads();
    if (tid == 0) {
      const int lt = tags[b * TT + len - 1];
      big[16] = big[0] + big[1] + big[2] + big[3] + trans[END_IDX * NN + lt];
    }
  } else {
    // w_{len-1} = exp(u_{len-1}) .* exp(trans[END,:])  (true values, sc=0)
    float wI = 0.f;
    if (erow) {
      wI = __expf(upj[(size_t)(len - 1) * NN] + trans[END_IDX * NN + jrow]);
      pH[0][wh] = (_Float16)wI;
    }
    const float mxI = wave_max_dpp((c < 6) ? wI : 0.f); // lane 63 valid
    if (lane == 63) *reinterpret_cast<float*>(&pH[0][wave * CH + 28]) = mxI;
  }

  // ---- u loader for iteration k's WRITE factor:
  // fwd: u_k (clamped); bwd: u_{len-2-k}, except final iteration -> 0 (factor 1)
  auto uload_k = [&](int k) -> float {
    if (!erow) return 0.f;
    if (isF) {
      const int kk = (k < nsteps) ? k : (nsteps - 1);
      return upj[(size_t)kk * NN];
    }
    if (k >= nsteps - 1) return 0.f;
    return upj[(size_t)(len - 2 - k) * NN];
  };

  float uexpC = erow ? __expf(uload_k(0)) : 0.f;
  float a0r = 0.f, a1r = uload_k(1);
  float sc2 = 0.f; // scale (log2): true = 2^sc2 * stored
  __syncthreads();

  auto STEP = [&](int k, float& con, float& iss) {
    const int rb = k & 1, wb = rb ^ 1;

    const _Float16* pc = &pH[rb][c * CH];
    const uint4 q0 = reinterpret_cast<const uint4*>(pc)[0];
    const uint4 q1 = reinterpret_cast<const uint4*>(pc)[1];
    const uint4 q2 = reinterpret_cast<const uint4*>(pc)[2];
    const uint4 q3 = *reinterpret_cast<const uint4*>(pc + 24); // data + pad

    iss = uload_k(k + 2); // issue early, consume late next step

    const float M = dpp_max8(__int_as_float(q3.z));
    const float rcpM = __builtin_amdgcn_rcpf(M);
    sc2 += __log2f(M);
    const float f = uexpC * rcpM;

    const unsigned pw[14] = {q0.x, q0.y, q0.z, q0.w, q1.x, q1.y, q1.z, q1.w,
                             q2.x, q2.y, q2.z, q2.w, q3.x, q3.y};
    float a0 = 0.f, a1 = 0.f, a2 = 0.f, a3 = 0.f, a4 = 0.f, a5 = 0.f, a6 = 0.f;
#pragma unroll
    for (int m = 0; m < QI / 2; ++m) {
      const v2h pk = __builtin_bit_cast(v2h, pw[m]);
      a0 = fdot2(Er[0][m], pk, a0);
      a1 = fdot2(Er[1][m], pk, a1);
      a2 = fdot2(Er[2][m], pk, a2);
      a3 = fdot2(Er[3][m], pk, a3);
      a4 = fdot2(Er[4][m], pk, a4);
      a5 = fdot2(Er[5][m], pk, a5);
      a6 = fdot2(Er[6][m], pk, a6);
    }
    const float s0 = dpp_add8(a0);
    const float s1 = dpp_add8(a1);
    const float s2 = dpp_add8(a2);
    const float s3 = dpp_add8(a3);
    const float s4 = dpp_add8(a4);
    const float s5 = dpp_add8(a5);
    const float s6 = dpp_add8(a6);
    float s = s0;
    s = (c == 1) ? s1 : s;
    s = (c == 2) ? s2 : s;
    s = (c == 3) ? s3 : s;
    s = (c == 4) ? s4 : s;
    s = (c == 5) ? s5 : s;
    s = (c == 6) ? s6 : s;

    const float pnew = s * f;
    if (erow) pH[wb][wh] = (_Float16)pnew;
    const float mx = wave_max_dpp((c < 6) ? pnew : 0.f); // lane 63 valid
    if (lane == 63)
      *reinterpret_cast<float*>(&pH[wb][wave * CH + 28]) = mx;

    uexpC = erow ? __expf(con) : 0.f;
    sync_lds();
  };

  int k = 0;
  for (; k + 1 < nsteps; k += 2) {
    STEP(k, a1r, a0r);
    STEP(k + 1, a0r, a1r);
  }
  if (k < nsteps) STEP(k, a1r, a0r);

  // ---- dump half-result: 200 fp32 values + scale (+ gold for fwd)
  const int fb = nsteps & 1;
  const size_t base = (size_t)b * 512 + (isF ? 0 : 256);
  if (tid < NN)
    ws[base + tid] = (float)pH[fb][(tid / QI) * CH + (tid % QI)];
  if (tid == 0) {
    ws[base + 200] = sc2;
    if (isF) ws[base + 201] = big[16];
  }
}

// Z_b = (scF+scB)*ln2 + log(aF . aB); out = mean(Z_b - gold_b)
__global__ void crf_merge_kernel(const float* __restrict__ ws,
                                 float* __restrict__ out) {
  const int tid = threadIdx.x; // 128 threads, one chain each
  const float* wf = ws + (size_t)tid * 512;
  float sum = 0.f;
#pragma unroll
  for (int i = 0; i < NN / 4; ++i) {
    const float4 a = reinterpret_cast<const float4*>(wf)[i];
    const float4 d = reinterpret_cast<const float4*>(wf + 256)[i];
    sum += a.x * d.x + a.y * d.y + a.z * d.z + a.w * d.w;
  }
  const float Z = (wf[200] + wf[456]) * 0.6931471805599453f + __logf(sum);
  float v = Z - wf[201];
#pragma unroll
  for (int k = 32; k >= 1; k >>= 1) v += __shfl_xor(v, k, 64);
  __shared__ float s2[2];
  if ((tid & 63) == 0) s2[tid >> 6] = v;
  __syncthreads();
  if (tid == 0) out[0] = (s2[0] + s2[1]) * (1.0f / 128.0f);
}

extern "C" void kernel_launch(void* const* d_in, const int* in_sizes, int n_in,
                              void* d_out, int out_size, void* d_ws, size_t ws_size,
                              hipStream_t stream) {
  const float* unary = (const float*)d_in[0];
  const int* tags = (const int*)d_in[1];
  const int* lengths = (const int*)d_in[2];
  const float* trans = (const float*)d_in[3];
  float* ws = (float*)d_ws;
  float* out = (float*)d_out;

  crf_half_kernel<<<2 * BB, NT, 0, stream>>>(unary, tags, lengths, trans, ws);
  crf_merge_kernel<<<1, 128, 0, stream>>>(ws, out);
}